// Round 2
// baseline (83.484 us; speedup 1.0000x reference)
//
#include <hip/hip_runtime.h>
#include <math.h>

#define BATCH 16384
#define OUTF  1024
#define INF   1024
#define KPROJ 256
#define MTOT  (BATCH + OUTF)   // 17408
#define NKT   16               // K-tiles of 64

#define NZ_THRESH 0.15f        // ~6.8 sigma of f16 dot error (sigma ~0.022)

typedef unsigned long long u64;
typedef unsigned short     u16;
typedef _Float16           f16;
typedef __attribute__((ext_vector_type(8))) _Float16 f16x8;
typedef __attribute__((ext_vector_type(4))) float    f32x4;

#define SCHED0() __builtin_amdgcn_sched_barrier(0)

// ---------------------------------------------------------------------------
// prep_p: P (256 x 1024) fp32 -> f16 in MFMA FRAGMENT ORDER.
// Fragment f = (kt*16 + j)*2 + ks holds, for lane = l4*16+l15, the 8 f16
// elements  B[col = j*16+l15][k = kt*64 + ks*32 + l4*8 .. +7].
// gemm then reads each fragment as ONE wave-contiguous 1KB dwordx4 burst.
// Block = one k-chunk c (k = c*8..c*8+7), thread = one col p.
// ---------------------------------------------------------------------------
__global__ __launch_bounds__(256) void prep_p(const float* __restrict__ P,
                                              f16* __restrict__ Bf) {
    const int c = blockIdx.x;      // 0..127
    const int p = threadIdx.x;     // 0..255 (= B col)
    const float4 f0 = *(const float4*)(P + (size_t)p * INF + c * 8);
    const float4 f1 = *(const float4*)(P + (size_t)p * INF + c * 8 + 4);
    const int kt = c >> 3, ks = (c >> 2) & 1, lq = c & 3;
    const int frag = (kt * 16 + (p >> 4)) * 2 + ks;
    const int lane = lq * 16 + (p & 15);
    f16x8 h;
    h[0] = (f16)f0.x; h[1] = (f16)f0.y; h[2] = (f16)f0.z; h[3] = (f16)f0.w;
    h[4] = (f16)f1.x; h[5] = (f16)f1.y; h[6] = (f16)f1.z; h[7] = (f16)f1.w;
    *(f16x8*)(Bf + (size_t)(frag * 64 + lane) * 8) = h;
}

// ---------------------------------------------------------------------------
// Barrier-free sign GEMM. One wave per block; each wave owns 16 rows x all
// 256 cols. A: wave-private, fp32 loaded to regs (prefetch distance = 1 full
// K-iter, issued at loop tail BEHIND the bf loads so the compiler's precise
// use-site waitcnt never drains it early), converted to f16 in-regs. B: read
// as register fragments straight from L2 (fragment-ordered Bf, each load a
// coalesced wave-wide 1KB dwordx4). No LDS staging, no barriers, no
// inter-wave coupling anywhere in the K-loop.
// Epilogue: norms via 2x shfl_xor; ballot sign-pack; rare fp64 re-dot fixup.
// ---------------------------------------------------------------------------
__global__ __launch_bounds__(64) void gemm_signs(const float* __restrict__ X,
                                                 const float* __restrict__ W,
                                                 const f16* __restrict__ Bf,
                                                 const float* __restrict__ Pf,
                                                 u64* __restrict__ cx,
                                                 u64* __restrict__ cw,
                                                 float* __restrict__ xn,
                                                 float* __restrict__ wn) {
    __shared__ u16 sw[16][16];

    const int lane = threadIdx.x;
    const int l4 = lane >> 4, l15 = lane & 15;
    const int row0 = blockIdx.x * 16;
    const float* Asrc = (row0 < BATCH) ? X + (size_t)row0 * INF
                                       : W + (size_t)(row0 - BATCH) * INF;
    // lane's A source: row l15 of the wave tile, k-chunk base l4*8
    const float* aPtr = Asrc + (size_t)l15 * INF + l4 * 8;
    const f16* bPtr = Bf + lane * 8;

    f32x4 acc[16] = {};
    float ssq = 0.0f;

#define GEMM_BODY(KT, Q0, Q1, Q2, Q3, DO_PF)                                  \
    {                                                                         \
        ssq += Q0.x * Q0.x + Q0.y * Q0.y + Q0.z * Q0.z + Q0.w * Q0.w +        \
               Q1.x * Q1.x + Q1.y * Q1.y + Q1.z * Q1.z + Q1.w * Q1.w +        \
               Q2.x * Q2.x + Q2.y * Q2.y + Q2.z * Q2.z + Q2.w * Q2.w +        \
               Q3.x * Q3.x + Q3.y * Q3.y + Q3.z * Q3.z + Q3.w * Q3.w;         \
        f16x8 a0, a1;                                                         \
        a0[0] = (f16)Q0.x; a0[1] = (f16)Q0.y; a0[2] = (f16)Q0.z;              \
        a0[3] = (f16)Q0.w; a0[4] = (f16)Q1.x; a0[5] = (f16)Q1.y;              \
        a0[6] = (f16)Q1.z; a0[7] = (f16)Q1.w;                                 \
        a1[0] = (f16)Q2.x; a1[1] = (f16)Q2.y; a1[2] = (f16)Q2.z;              \
        a1[3] = (f16)Q2.w; a1[4] = (f16)Q3.x; a1[5] = (f16)Q3.y;              \
        a1[6] = (f16)Q3.z; a1[7] = (f16)Q3.w;                                 \
        const f16* bk = bPtr + (size_t)(KT) * 16384;                          \
        _Pragma("unroll")                                                     \
        for (int jb = 0; jb < 4; ++jb) {                                      \
            f16x8 b0 = *(const f16x8*)(bk + (jb * 4 + 0) * 1024);             \
            f16x8 b1 = *(const f16x8*)(bk + (jb * 4 + 0) * 1024 + 512);       \
            f16x8 b2 = *(const f16x8*)(bk + (jb * 4 + 1) * 1024);             \
            f16x8 b3 = *(const f16x8*)(bk + (jb * 4 + 1) * 1024 + 512);       \
            f16x8 b4 = *(const f16x8*)(bk + (jb * 4 + 2) * 1024);             \
            f16x8 b5 = *(const f16x8*)(bk + (jb * 4 + 2) * 1024 + 512);       \
            f16x8 b6 = *(const f16x8*)(bk + (jb * 4 + 3) * 1024);             \
            f16x8 b7 = *(const f16x8*)(bk + (jb * 4 + 3) * 1024 + 512);       \
            acc[jb * 4 + 0] = __builtin_amdgcn_mfma_f32_16x16x32_f16(         \
                a0, b0, acc[jb * 4 + 0], 0, 0, 0);                            \
            acc[jb * 4 + 0] = __builtin_amdgcn_mfma_f32_16x16x32_f16(         \
                a1, b1, acc[jb * 4 + 0], 0, 0, 0);                            \
            acc[jb * 4 + 1] = __builtin_amdgcn_mfma_f32_16x16x32_f16(         \
                a0, b2, acc[jb * 4 + 1], 0, 0, 0);                            \
            acc[jb * 4 + 1] = __builtin_amdgcn_mfma_f32_16x16x32_f16(         \
                a1, b3, acc[jb * 4 + 1], 0, 0, 0);                            \
            acc[jb * 4 + 2] = __builtin_amdgcn_mfma_f32_16x16x32_f16(         \
                a0, b4, acc[jb * 4 + 2], 0, 0, 0);                            \
            acc[jb * 4 + 2] = __builtin_amdgcn_mfma_f32_16x16x32_f16(         \
                a1, b5, acc[jb * 4 + 2], 0, 0, 0);                            \
            acc[jb * 4 + 3] = __builtin_amdgcn_mfma_f32_16x16x32_f16(         \
                a0, b6, acc[jb * 4 + 3], 0, 0, 0);                            \
            acc[jb * 4 + 3] = __builtin_amdgcn_mfma_f32_16x16x32_f16(         \
                a1, b7, acc[jb * 4 + 3], 0, 0, 0);                            \
        }                                                                     \
        if (DO_PF) {                                                          \
            SCHED0();                                                         \
            Q0 = *(const float4*)(aPtr + ((KT) + 2) * 64);                    \
            Q1 = *(const float4*)(aPtr + ((KT) + 2) * 64 + 4);                \
            Q2 = *(const float4*)(aPtr + ((KT) + 2) * 64 + 32);               \
            Q3 = *(const float4*)(aPtr + ((KT) + 2) * 64 + 36);               \
            SCHED0();                                                         \
        }                                                                     \
    }

    // prologue: tiles 0 and 1 in flight
    float4 qa0 = *(const float4*)(aPtr);
    float4 qa1 = *(const float4*)(aPtr + 4);
    float4 qa2 = *(const float4*)(aPtr + 32);
    float4 qa3 = *(const float4*)(aPtr + 36);
    float4 qb0 = *(const float4*)(aPtr + 64);
    float4 qb1 = *(const float4*)(aPtr + 68);
    float4 qb2 = *(const float4*)(aPtr + 96);
    float4 qb3 = *(const float4*)(aPtr + 100);

    for (int kt = 0; kt < 12; kt += 2) {
        GEMM_BODY(kt,     qa0, qa1, qa2, qa3, true);
        GEMM_BODY(kt + 1, qb0, qb1, qb2, qb3, true);
    }
    GEMM_BODY(12, qa0, qa1, qa2, qa3, true);    // loads tile 14 -> qa
    GEMM_BODY(13, qb0, qb1, qb2, qb3, true);    // loads tile 15 -> qb
    GEMM_BODY(14, qa0, qa1, qa2, qa3, false);
    GEMM_BODY(15, qb0, qb1, qb2, qb3, false);

    // ---- row norms: rows are lane-private (row = row0 + l15) ----
    {
        float s = ssq;
        s += __shfl_xor(s, 16, 64);
        s += __shfl_xor(s, 32, 64);
        if (lane < 16) {
            const int grow = row0 + lane;
            const float n = sqrtf(s) + 1.1920929e-07f;
            if (grow < BATCH) xn[grow] = n; else wn[grow - BATCH] = n;
        }
    }

    // ---- sign pack + fused fp64 fixup for near-zero dots ----
    // C layout: local row = l4*4 + q, col = j*16 + l15.
#pragma unroll
    for (int j = 0; j < 16; ++j)
#pragma unroll
        for (int q = 0; q < 4; ++q) {
            const float v = acc[j][q];
            int bit = (v >= 0.0f) ? 1 : 0;
            u64 fl = __ballot(fabsf(v) < NZ_THRESH);
            while (fl) {   // rare (~15/wave): whole wave re-dots in fp64
                const int src = __ffsll((long long)fl) - 1;
                fl &= fl - 1;
                const int lrow = ((src >> 4) << 2) + q;
                const int col  = j * 16 + (src & 15);
                const float* xr = Asrc + (size_t)lrow * INF + lane * 16;
                const float* pr = Pf + (size_t)col * INF + lane * 16;
                double s = 0.0;
#pragma unroll
                for (int c4 = 0; c4 < 4; ++c4) {
                    float4 xa = *(const float4*)(xr + c4 * 4);
                    float4 pa = *(const float4*)(pr + c4 * 4);
                    s += (double)xa.x * pa.x + (double)xa.y * pa.y +
                         (double)xa.z * pa.z + (double)xa.w * pa.w;
                }
#pragma unroll
                for (int off = 32; off; off >>= 1) s += __shfl_xor(s, off, 64);
                if (lane == src) bit = (s >= 0.0) ? 1 : 0;
            }
            const u64 b = __ballot(bit != 0);
            if (l15 == 0)
                sw[l4 * 4 + q][j] = (u16)(b >> (l4 * 16));
        }
    __syncthreads();
    {
        const int r = lane >> 2, w = lane & 3;
        const u64 val = *(const u64*)&sw[r][w * 4];
        const int grow = row0 + r;
        if (grow < BATCH) cx[(size_t)grow * 4 + w] = val;
        else              cw[(size_t)(grow - BATCH) * 4 + w] = val;
    }
}

// ---------------------------------------------------------------------------
// out[b][m] = xn[b] * wn[m] * cos(pi * popc / 256)
// ---------------------------------------------------------------------------
__global__ __launch_bounds__(256) void popc_out(const u64* __restrict__ cx,
                                                const u64* __restrict__ cw,
                                                const float* __restrict__ xn,
                                                const float* __restrict__ wn,
                                                float* __restrict__ out) {
    __shared__ float lut[257];
    __shared__ u64 cxs[64][4];
    __shared__ float xns[64];
    const int t = threadIdx.x;

    lut[t] = (float)cos((double)t * (3.14159265358979323846 / 256.0));
    if (t == 0) lut[256] = -1.0f;

    const int r0 = blockIdx.x * 64;
    cxs[t >> 2][t & 3] = cx[(size_t)r0 * 4 + t];
    if (t < 64) xns[t] = xn[r0 + t];

    const ulonglong4* cwv4 = (const ulonglong4*)cw;
    ulonglong4 c0 = cwv4[4 * t + 0];
    ulonglong4 c1 = cwv4[4 * t + 1];
    ulonglong4 c2 = cwv4[4 * t + 2];
    ulonglong4 c3 = cwv4[4 * t + 3];
    float4 wnr = ((const float4*)wn)[t];

    __syncthreads();

    float4* outv = (float4*)out;
    const size_t obase = (size_t)r0 * (OUTF / 4) + t;
#pragma unroll 4
    for (int r = 0; r < 64; ++r) {
        const u64 a0 = cxs[r][0], a1 = cxs[r][1], a2 = cxs[r][2], a3 = cxs[r][3];
        const float sx = xns[r];
        float4 o;
        o.x = sx * wnr.x * lut[__popcll(a0 ^ c0.x) + __popcll(a1 ^ c0.y) +
                               __popcll(a2 ^ c0.z) + __popcll(a3 ^ c0.w)];
        o.y = sx * wnr.y * lut[__popcll(a0 ^ c1.x) + __popcll(a1 ^ c1.y) +
                               __popcll(a2 ^ c1.z) + __popcll(a3 ^ c1.w)];
        o.z = sx * wnr.z * lut[__popcll(a0 ^ c2.x) + __popcll(a1 ^ c2.y) +
                               __popcll(a2 ^ c2.z) + __popcll(a3 ^ c2.w)];
        o.w = sx * wnr.w * lut[__popcll(a0 ^ c3.x) + __popcll(a1 ^ c3.y) +
                               __popcll(a2 ^ c3.z) + __popcll(a3 ^ c3.w)];
        outv[obase + (size_t)r * (OUTF / 4)] = o;
    }
}

extern "C" void kernel_launch(void* const* d_in, const int* in_sizes, int n_in,
                              void* d_out, int out_size, void* d_ws, size_t ws_size,
                              hipStream_t stream) {
    const float* x = (const float*)d_in[0];
    const float* w = (const float*)d_in[1];
    const float* P = (const float*)d_in[2];
    float* out = (float*)d_out;

    char* ws = (char*)d_ws;
    f16*  Bf = (f16*)ws;                         // +0        (524288 B)
    u64*  cx = (u64*)(ws + 524288);              // +524288   (524288 B)
    u64*  cw = (u64*)(ws + 1048576);             // +1048576  (32768 B)
    float* xn = (float*)(ws + 1081344);          // +1081344  (65536 B)
    float* wn = (float*)(ws + 1146880);          // +1146880  (4096 B)

    prep_p<<<128, 256, 0, stream>>>(P, Bf);

    gemm_signs<<<MTOT / 16, 64, 0, stream>>>(x, w, Bf, P, cx, cw, xn, wn);

    popc_out<<<BATCH / 64, 256, 0, stream>>>(cx, cw, xn, wn, out);
}